// Round 2
// baseline (8975.101 us; speedup 1.0000x reference)
//
#include <hip/hip_runtime.h>
#include <math.h>

#define N_ROWS 10816   // 64 * 169 rows per timestep
#define T_SEQ 55
#define NPIX 169

__device__ __forceinline__ float sigmoidf_(float x){ return 1.0f/(1.0f+expf(-x)); }

// ---------------------------------------------------------------------------
// Kernel 1: fused input transpose + 4x (1x1 conv + ReLU) chain.
// Writes out in channel-major layout: out[(l*30+co)*N_ROWS + n], n = b*169+p.
// ---------------------------------------------------------------------------
__global__ __launch_bounds__(256) void conv1x1_chain(
    const float* __restrict__ x,
    const float* __restrict__ w0, const float* __restrict__ b0,
    const float* __restrict__ w1, const float* __restrict__ b1,
    const float* __restrict__ w2, const float* __restrict__ b2,
    const float* __restrict__ w3, const float* __restrict__ b3,
    float* __restrict__ out)
{
    int n = blockIdx.x*256 + threadIdx.x;
    int l = blockIdx.y;
    if (n >= N_ROWS) return;
    // x layout: [b][13][13][l][c] -> flat ((b*169+p)*55 + l)*24 = (n*55+l)*24
    const float* xp = x + ((size_t)n*T_SEQ + l)*24;
    float in24[24];
    #pragma unroll
    for (int i=0;i<6;i++){
        float4 v = *(const float4*)(xp + 4*i);
        in24[4*i]=v.x; in24[4*i+1]=v.y; in24[4*i+2]=v.z; in24[4*i+3]=v.w;
    }
    float a[30], c[30];
    #pragma unroll
    for (int co=0;co<30;co++) a[co]=b0[co];
    #pragma unroll
    for (int ci=0;ci<24;ci++){
        float v = in24[ci];
        #pragma unroll
        for (int co=0;co<30;co++) a[co] = fmaf(v, w0[ci*30+co], a[co]);
    }
    #pragma unroll
    for (int co=0;co<30;co++) a[co] = fmaxf(a[co],0.f);

#define LAYER30(wp, bp) \
    { _Pragma("unroll") for (int co=0;co<30;co++) c[co]=(bp)[co]; \
      _Pragma("unroll") for (int ci=0;ci<30;ci++){ float v=a[ci]; \
        _Pragma("unroll") for (int co=0;co<30;co++) c[co]=fmaf(v,(wp)[ci*30+co],c[co]); } \
      _Pragma("unroll") for (int co=0;co<30;co++) a[co]=fmaxf(c[co],0.f); }

    LAYER30(w1,b1);
    LAYER30(w2,b2);
    LAYER30(w3,b3);
#undef LAYER30

    float* op = out + (size_t)l*30*N_ROWS + n;
    #pragma unroll
    for (int co=0;co<30;co++) op[(size_t)co*N_ROWS] = a[co];
}

// ---------------------------------------------------------------------------
// Kernel 2: 5x5 SAME conv + ReLU, channel-major layout, IN-PLACE.
// One block per image (grid = 55*64 = 3520). Each block stages its entire
// input image into padded LDS behind a barrier, then overwrites the same
// global region. No cross-block data dependencies -> in-place is safe and
// halves the workspace footprint (ws overflow was the suspected R1 crash).
// ---------------------------------------------------------------------------
__global__ __launch_bounds__(192) void conv5x5(
    float* __restrict__ buf, const float* __restrict__ w,
    const float* __restrict__ bias)
{
    __shared__ float img[30*17*17];   // [ci][yy][xx], 2-halo, zero padded
    int bi = blockIdx.x;
    int l = bi >> 6;           // / 64
    int b = bi & 63;
    float* ip = buf + (size_t)l*30*N_ROWS + (size_t)b*NPIX;
    int tid = threadIdx.x;
    for (int i = tid; i < 30*289; i += 192) img[i] = 0.f;
    __syncthreads();
    for (int i = tid; i < 30*169; i += 192){
        int ci = i/169, p = i - ci*169;
        int y = p/13, xx = p - y*13;
        img[ci*289 + (y+2)*17 + (xx+2)] = ip[(size_t)ci*N_ROWS + p];
    }
    __syncthreads();

    int p = tid;
    bool act = p < 169;
    int pc = act ? p : 0;
    int y = pc/13, x0 = pc - y*13;

    float acc[30];
    #pragma unroll
    for (int co=0;co<30;co++) acc[co]=bias[co];

    for (int dy=0; dy<5; dy++){
      for (int dx=0; dx<5; dx++){
        const float* wp = w + (size_t)((dy*5+dx)*30)*30;
        const float* im = img + (y+dy)*17 + (x0+dx);
        #pragma unroll
        for (int ci=0; ci<30; ci++){
          float v = im[ci*289];
          #pragma unroll
          for (int co=0;co<30;co++) acc[co] = fmaf(v, wp[ci*30+co], acc[co]);
        }
      }
    }
    if (act){
      #pragma unroll
      for (int co=0;co<30;co++) ip[(size_t)co*N_ROWS + p] = fmaxf(acc[co],0.f);
    }
}

// ---------------------------------------------------------------------------
// Kernel 3: one LSTM step (fused GEMM + gates). TF gate order (i,j,f,o),
// forget bias 1.0. Thread = 1 row x 10 base cols x 4 gates (40 accs).
// Optionally fuses the final 1x1 projection (layer 2) via atomicAdd.
// All state tensors: [hdim][N_ROWS].
// ---------------------------------------------------------------------------
template<int DX>
__global__ __launch_bounds__(256) void lstm_step(
    const float* __restrict__ xT,    // [DX][N]
    const float* __restrict__ hprev, // [100][N]
    float* __restrict__ hnew,        // [100][N]
    float* __restrict__ cst,         // [100][N] (in-place)
    const float* __restrict__ W,     // [(DX+100)][400]
    const float* __restrict__ bias,  // [400]
    const float* __restrict__ we,    // [100] or nullptr
    const float* __restrict__ be,    // [1] or nullptr
    float* __restrict__ outp, int l)
{
    int tid = threadIdx.x;
    int row = blockIdx.x*256 + tid;
    int c0 = blockIdx.y*10;
    bool act = row < N_ROWS;
    int rr = act ? row : 0;

    float acc[4][10];
    #pragma unroll
    for (int g=0; g<4; g++)
      #pragma unroll
      for (int j=0; j<10; j++) acc[g][j] = bias[g*100 + c0 + j];

    #pragma unroll 5
    for (int k=0; k<DX; k++){
        float a = xT[(size_t)k*N_ROWS + rr];
        const float* wp = W + (size_t)k*400 + c0;
        #pragma unroll
        for (int g=0; g<4; g++)
          #pragma unroll
          for (int j=0; j<10; j++)
            acc[g][j] = fmaf(a, wp[g*100+j], acc[g][j]);
    }
    #pragma unroll 5
    for (int k=0; k<100; k++){
        float a = hprev[(size_t)k*N_ROWS + rr];
        const float* wp = W + (size_t)(DX+k)*400 + c0;
        #pragma unroll
        for (int g=0; g<4; g++)
          #pragma unroll
          for (int j=0; j<10; j++)
            acc[g][j] = fmaf(a, wp[g*100+j], acc[g][j]);
    }

    if (!act) return;
    float partial = 0.f;
    #pragma unroll
    for (int j=0; j<10; j++){
        int col = c0 + j;
        size_t idx = (size_t)col*N_ROWS + row;
        float cold = cst[idx];
        float gi = sigmoidf_(acc[0][j]);
        float gj = tanhf(acc[1][j]);
        float gf = sigmoidf_(acc[2][j] + 1.0f);
        float go = sigmoidf_(acc[3][j]);
        float cn = gf*cold + gi*gj;
        cst[idx] = cn;
        float h = go*tanhf(cn);
        hnew[idx] = h;
        if (we) partial = fmaf(h, we[col], partial);
    }
    if (we){
        if (blockIdx.y == 0) partial += be[0];
        atomicAdd(outp + (size_t)row*T_SEQ + l, partial);
    }
}

// ---------------------------------------------------------------------------
extern "C" void kernel_launch(void* const* d_in, const int* in_sizes, int n_in,
                              void* d_out, int out_size, void* d_ws, size_t ws_size,
                              hipStream_t stream)
{
    const float* x    = (const float*)d_in[0];
    const float* w10  = (const float*)d_in[1];  const float* b10 = (const float*)d_in[2];
    const float* w11  = (const float*)d_in[3];  const float* b11 = (const float*)d_in[4];
    const float* w12  = (const float*)d_in[5];  const float* b12 = (const float*)d_in[6];
    const float* w13  = (const float*)d_in[7];  const float* b13 = (const float*)d_in[8];
    const float* w20  = (const float*)d_in[9];  const float* b20 = (const float*)d_in[10];
    const float* w21  = (const float*)d_in[11]; const float* b21 = (const float*)d_in[12];
    const float* w22  = (const float*)d_in[13]; const float* b22 = (const float*)d_in[14];
    const float* w23  = (const float*)d_in[15]; const float* b23 = (const float*)d_in[16];
    const float* l1w  = (const float*)d_in[17]; const float* l1b = (const float*)d_in[18];
    const float* l2w  = (const float*)d_in[19]; const float* l2b = (const float*)d_in[20];
    const float* we   = (const float*)d_in[21]; const float* be  = (const float*)d_in[22];
    float* out = (float*)d_out;

    // workspace layout (floats): single conv slab (in-place 5x5) + LSTM state
    // = 71.4 MB + 25.9 MB = 97.4 MB total.
    const size_t NF = (size_t)30*N_ROWS;           // per-timestep conv slab
    float* buf0 = (float*)d_ws;                    // [55][30][N]
    float* st   = buf0 + (size_t)T_SEQ*NF;
    const size_t HS = (size_t)100*N_ROWS;
    float* h1a = st;            float* h1b = h1a + HS;
    float* c1  = h1b + HS;
    float* h2a = c1 + HS;       float* h2b = h2a + HS;
    float* c2  = h2b + HS;

    hipMemsetAsync(d_out, 0, (size_t)out_size*sizeof(float), stream);
    hipMemsetAsync(h1a, 0, HS*sizeof(float), stream);
    hipMemsetAsync(c1,  0, HS*sizeof(float), stream);
    hipMemsetAsync(h2a, 0, HS*sizeof(float), stream);
    hipMemsetAsync(c2,  0, HS*sizeof(float), stream);

    // conv stack
    dim3 g1((N_ROWS+255)/256, T_SEQ);
    conv1x1_chain<<<g1, 256, 0, stream>>>(x, w10,b10, w11,b11, w12,b12, w13,b13, buf0);
    conv5x5<<<T_SEQ*64, 192, 0, stream>>>(buf0, w20, b20);
    conv5x5<<<T_SEQ*64, 192, 0, stream>>>(buf0, w21, b21);
    conv5x5<<<T_SEQ*64, 192, 0, stream>>>(buf0, w22, b22);
    conv5x5<<<T_SEQ*64, 192, 0, stream>>>(buf0, w23, b23);

    // LSTM stack, interleaved per timestep; layer2 fuses final projection.
    dim3 gl((N_ROWS+255)/256, 10);
    for (int t=0; t<T_SEQ; t++){
        const float* xT = buf0 + (size_t)t*NF;
        float* hp1 = (t&1) ? h1b : h1a;
        float* hn1 = (t&1) ? h1a : h1b;
        lstm_step<30><<<gl, 256, 0, stream>>>(xT, hp1, hn1, c1, l1w, l1b,
                                              nullptr, nullptr, nullptr, 0);
        float* hp2 = (t&1) ? h2b : h2a;
        float* hn2 = (t&1) ? h2a : h2b;
        lstm_step<100><<<gl, 256, 0, stream>>>(hn1, hp2, hn2, c2, l2w, l2b,
                                               we, be, out, t);
    }
}

// Round 3
// 5837.881 us; speedup vs baseline: 1.5374x; 1.5374x over previous
//
#include <hip/hip_runtime.h>
#include <math.h>

#define N_ROWS 10816   // 64 * 169 rows per timestep
#define T_SEQ 55
#define NPIX 169

__device__ __forceinline__ float sigmoidf_(float x){ return 1.0f/(1.0f+expf(-x)); }

// ---------------------------------------------------------------------------
// Kernel 1: fused input transpose + 4x (1x1 conv + ReLU) chain.
// Writes channel-major: out[(l*30+co)*N_ROWS + n], n = b*169+p.
// ---------------------------------------------------------------------------
__global__ __launch_bounds__(256) void conv1x1_chain(
    const float* __restrict__ x,
    const float* __restrict__ w0, const float* __restrict__ b0,
    const float* __restrict__ w1, const float* __restrict__ b1,
    const float* __restrict__ w2, const float* __restrict__ b2,
    const float* __restrict__ w3, const float* __restrict__ b3,
    float* __restrict__ out)
{
    int n = blockIdx.x*256 + threadIdx.x;
    int l = blockIdx.y;
    if (n >= N_ROWS) return;
    const float* xp = x + ((size_t)n*T_SEQ + l)*24;
    float in24[24];
    #pragma unroll
    for (int i=0;i<6;i++){
        float4 v = *(const float4*)(xp + 4*i);
        in24[4*i]=v.x; in24[4*i+1]=v.y; in24[4*i+2]=v.z; in24[4*i+3]=v.w;
    }
    float a[30], c[30];
    #pragma unroll
    for (int co=0;co<30;co++) a[co]=b0[co];
    #pragma unroll
    for (int ci=0;ci<24;ci++){
        float v = in24[ci];
        #pragma unroll
        for (int co=0;co<30;co++) a[co] = fmaf(v, w0[ci*30+co], a[co]);
    }
    #pragma unroll
    for (int co=0;co<30;co++) a[co] = fmaxf(a[co],0.f);

#define LAYER30(wp, bp) \
    { _Pragma("unroll") for (int co=0;co<30;co++) c[co]=(bp)[co]; \
      _Pragma("unroll") for (int ci=0;ci<30;ci++){ float v=a[ci]; \
        _Pragma("unroll") for (int co=0;co<30;co++) c[co]=fmaf(v,(wp)[ci*30+co],c[co]); } \
      _Pragma("unroll") for (int co=0;co<30;co++) a[co]=fmaxf(c[co],0.f); }

    LAYER30(w1,b1);
    LAYER30(w2,b2);
    LAYER30(w3,b3);
#undef LAYER30

    float* op = out + (size_t)l*30*N_ROWS + n;
    #pragma unroll
    for (int co=0;co<30;co++) op[(size_t)co*N_ROWS] = a[co];
}

// ---------------------------------------------------------------------------
// Kernel 2: 5x5 SAME conv + ReLU, channel-major, IN-PLACE, TWO-PHASE staging.
// LDS holds 15 channels at a time (17.3 KB vs 34.8 KB) -> ~9 blocks/CU,
// occupancy cap 12 -> 27 waves/CU. Halo is zeroed once; staging only
// rewrites interior cells, so the halo stays zero for both phases.
// ---------------------------------------------------------------------------
__global__ __launch_bounds__(192) void conv5x5(
    float* __restrict__ buf, const float* __restrict__ w,
    const float* __restrict__ bias)
{
    __shared__ float img[15*289];   // [ci][yy*17+xx], 2-halo
    int bi = blockIdx.x;
    int l = bi >> 6;
    int b = bi & 63;
    float* ip = buf + (size_t)l*30*N_ROWS + (size_t)b*NPIX;
    int tid = threadIdx.x;

    int p = tid;
    bool act = p < 169;
    int pc = act ? p : 0;
    int y = pc/13, x0 = pc - y*13;

    float acc[30];
    #pragma unroll
    for (int co=0;co<30;co++) acc[co]=bias[co];

    for (int i = tid; i < 15*289; i += 192) img[i] = 0.f;

    for (int half = 0; half < 2; half++){
        __syncthreads();     // (half==1) protect img from prior compute reads
        for (int i = tid; i < 15*169; i += 192){
            int ci = i/169, pp = i - ci*169;
            int yy = pp/13, xx = pp - yy*13;
            img[ci*289 + (yy+2)*17 + (xx+2)] =
                ip[(size_t)(half*15 + ci)*N_ROWS + pp];
        }
        __syncthreads();
        for (int dy=0; dy<5; dy++){
          for (int dx=0; dx<5; dx++){
            const float* wp = w + (size_t)((dy*5+dx)*30 + half*15)*30;
            const float* im = img + (y+dy)*17 + (x0+dx);
            #pragma unroll
            for (int ci=0; ci<15; ci++){
              float v = im[ci*289];
              #pragma unroll
              for (int co=0;co<30;co++) acc[co] = fmaf(v, wp[ci*30+co], acc[co]);
            }
          }
        }
    }
    if (act){
      #pragma unroll
      for (int co=0;co<30;co++) ip[(size_t)co*N_ROWS + p] = fmaxf(acc[co],0.f);
    }
}

// ---------------------------------------------------------------------------
// Kernel 3: one LSTM step. Col-tile 5 (grid 43x20 = 860 blocks -> 13.4
// waves/CU). Block's 20 gate-cols of W staged in LDS once (<=16 KB), read
// as wave-uniform float4 broadcasts (no SGPR s_load pressure). Activations
// prefetched in chunks of 10 (10 VMEM in flight per wave).
// Thread = 1 row x 5 base cols x 4 gates (20 accs). Layer-2 variant fuses
// the final 1x1 projection via atomicAdd into transposed output.
// State tensors: [hdim][N_ROWS].
// ---------------------------------------------------------------------------
template<int DX>
__global__ __launch_bounds__(256) void lstm_step(
    const float* __restrict__ xT,    // [DX][N]
    const float* __restrict__ hprev, // [100][N]
    float* __restrict__ hnew,        // [100][N]
    float* __restrict__ cst,         // [100][N] (in-place)
    const float* __restrict__ W,     // [(DX+100)][400]
    const float* __restrict__ bias,  // [400]
    const float* __restrict__ we,    // [100] or nullptr
    const float* __restrict__ be,    // [1] or nullptr
    float* __restrict__ outp, int l)
{
    constexpr int KK = DX + 100;
    __shared__ float wlds[KK*20];    // [k][20 packed gate-cols]
    int tid = threadIdx.x;
    int row = blockIdx.x*256 + tid;
    int c0 = blockIdx.y*5;

    for (int i = tid; i < KK*20; i += 256){
        int k = i / 20, r = i - k*20;
        int g = r / 5, j = r - g*5;
        wlds[i] = W[(size_t)k*400 + g*100 + c0 + j];
    }
    __syncthreads();

    bool act = row < N_ROWS;
    int rr = act ? row : 0;

    float acc[20];
    #pragma unroll
    for (int g=0; g<4; g++)
      #pragma unroll
      for (int j=0; j<5; j++) acc[g*5+j] = bias[g*100 + c0 + j];

    // ---- x part, then h part; chunked by 10 (all lens are multiples of 10)
    #pragma unroll 1
    for (int part = 0; part < 2; part++){
        const float* sptr = part ? hprev : xT;
        const int klen = part ? 100 : DX;
        const int kbase = part ? DX : 0;
        #pragma unroll 1
        for (int k0 = 0; k0 < klen; k0 += 10){
            float a[10];
            #pragma unroll
            for (int u=0; u<10; u++)
                a[u] = sptr[(size_t)(k0+u)*N_ROWS + rr];
            #pragma unroll
            for (int u=0; u<10; u++){
                const float* wp = wlds + (size_t)(kbase+k0+u)*20;
                float wv[20];
                #pragma unroll
                for (int t4=0; t4<5; t4++){
                    float4 v = *(const float4*)(wp + 4*t4);
                    wv[4*t4]=v.x; wv[4*t4+1]=v.y; wv[4*t4+2]=v.z; wv[4*t4+3]=v.w;
                }
                #pragma unroll
                for (int q=0; q<20; q++)
                    acc[q] = fmaf(a[u], wv[q], acc[q]);
            }
        }
    }

    if (!act) return;
    float partial = 0.f;
    #pragma unroll
    for (int j=0; j<5; j++){
        int col = c0 + j;
        size_t idx = (size_t)col*N_ROWS + row;
        float cold = cst[idx];
        float gi = sigmoidf_(acc[j]);
        float gj = tanhf(acc[5+j]);
        float gf = sigmoidf_(acc[10+j] + 1.0f);
        float go = sigmoidf_(acc[15+j]);
        float cn = gf*cold + gi*gj;
        cst[idx] = cn;
        float h = go*tanhf(cn);
        hnew[idx] = h;
        if (we) partial = fmaf(h, we[col], partial);
    }
    if (we){
        if (blockIdx.y == 0) partial += be[0];
        atomicAdd(outp + (size_t)row*T_SEQ + l, partial);
    }
}

// ---------------------------------------------------------------------------
extern "C" void kernel_launch(void* const* d_in, const int* in_sizes, int n_in,
                              void* d_out, int out_size, void* d_ws, size_t ws_size,
                              hipStream_t stream)
{
    const float* x    = (const float*)d_in[0];
    const float* w10  = (const float*)d_in[1];  const float* b10 = (const float*)d_in[2];
    const float* w11  = (const float*)d_in[3];  const float* b11 = (const float*)d_in[4];
    const float* w12  = (const float*)d_in[5];  const float* b12 = (const float*)d_in[6];
    const float* w13  = (const float*)d_in[7];  const float* b13 = (const float*)d_in[8];
    const float* w20  = (const float*)d_in[9];  const float* b20 = (const float*)d_in[10];
    const float* w21  = (const float*)d_in[11]; const float* b21 = (const float*)d_in[12];
    const float* w22  = (const float*)d_in[13]; const float* b22 = (const float*)d_in[14];
    const float* w23  = (const float*)d_in[15]; const float* b23 = (const float*)d_in[16];
    const float* l1w  = (const float*)d_in[17]; const float* l1b = (const float*)d_in[18];
    const float* l2w  = (const float*)d_in[19]; const float* l2b = (const float*)d_in[20];
    const float* we   = (const float*)d_in[21]; const float* be  = (const float*)d_in[22];
    float* out = (float*)d_out;

    // workspace: single conv slab (in-place 5x5) + LSTM state = 97.4 MB
    const size_t NF = (size_t)30*N_ROWS;
    float* buf0 = (float*)d_ws;                    // [55][30][N]
    float* st   = buf0 + (size_t)T_SEQ*NF;
    const size_t HS = (size_t)100*N_ROWS;
    float* h1a = st;            float* h1b = h1a + HS;
    float* c1  = h1b + HS;
    float* h2a = c1 + HS;       float* h2b = h2a + HS;
    float* c2  = h2b + HS;

    hipMemsetAsync(d_out, 0, (size_t)out_size*sizeof(float), stream);
    hipMemsetAsync(h1a, 0, HS*sizeof(float), stream);
    hipMemsetAsync(c1,  0, HS*sizeof(float), stream);
    hipMemsetAsync(h2a, 0, HS*sizeof(float), stream);
    hipMemsetAsync(c2,  0, HS*sizeof(float), stream);

    dim3 g1((N_ROWS+255)/256, T_SEQ);
    conv1x1_chain<<<g1, 256, 0, stream>>>(x, w10,b10, w11,b11, w12,b12, w13,b13, buf0);
    conv5x5<<<T_SEQ*64, 192, 0, stream>>>(buf0, w20, b20);
    conv5x5<<<T_SEQ*64, 192, 0, stream>>>(buf0, w21, b21);
    conv5x5<<<T_SEQ*64, 192, 0, stream>>>(buf0, w22, b22);
    conv5x5<<<T_SEQ*64, 192, 0, stream>>>(buf0, w23, b23);

    dim3 gl((N_ROWS+255)/256, 20);
    for (int t=0; t<T_SEQ; t++){
        const float* xT = buf0 + (size_t)t*NF;
        float* hp1 = (t&1) ? h1b : h1a;
        float* hn1 = (t&1) ? h1a : h1b;
        lstm_step<30><<<gl, 256, 0, stream>>>(xT, hp1, hn1, c1, l1w, l1b,
                                              nullptr, nullptr, nullptr, 0);
        float* hp2 = (t&1) ? h2b : h2a;
        float* hn2 = (t&1) ? h2a : h2b;
        lstm_step<100><<<gl, 256, 0, stream>>>(hn1, hp2, hn2, c2, l2w, l2b,
                                               we, be, out, t);
    }
}